// Round 15
// baseline (99.812 us; speedup 1.0000x reference)
//
#include <hip/hip_runtime.h>
#include <stdint.h>

#define NC 12
#define NHW (256*256)
#define XROW (130*12)        // ushorts per tap-row of the x tile [6][130][12]
// Wfold LDS layout, XOR-swizzled so A-fragment reads (row varies per lane,
// col fixed) are 2-way instead of 16-way bank conflicts (T2 pattern):
#define WSWZ(row, col) ((row)*128 + ((col) ^ (((row)&7)<<3)))

typedef __attribute__((ext_vector_type(8))) short bf16x8;
typedef __attribute__((ext_vector_type(4))) float f32x4;
typedef __attribute__((ext_vector_type(4))) uint32_t u32x4;
typedef __attribute__((ext_vector_type(2))) __bf16 bf16x2v;

// hot-path pack -> single v_cvt_pk_bf16_f32
__device__ __forceinline__ uint32_t pkbf(float lo, float hi) {
    uint32_t r;
    asm("v_cvt_pk_bf16_f32 %0, %1, %2" : "=v"(r) : "v"(lo), "v"(hi));
    return r;
}
// cold-path pack (setup, once)
__device__ __forceinline__ uint32_t pkbf_c(float lo, float hi) {
    bf16x2v v = { (__bf16)lo, (__bf16)hi };
    return __builtin_bit_cast(uint32_t, v);
}
__device__ __forceinline__ unsigned short bf16u(float f) {
    __bf16 b = (__bf16)f;
    return __builtin_bit_cast(unsigned short, b);
}
// opaque "v" pin (r6-verified; "a" = r12 scratch catastrophe, never again)
#define PIN(v) asm volatile("" : "+v"(v))

// perception filters (cross-correlation orientation, verified by r1-r14 passing)
__device__ constexpr float FI[3][3] = {{0,0,0},{0,1,0},{0,0,0}};
__device__ constexpr float FX[3][3] = {{-1,0,1},{-2,0,2},{-1,0,1}};
__device__ constexpr float FY[3][3] = {{-1,-2,-1},{0,0,0},{1,2,1}};
__device__ constexpr float FL[3][3] = {{1,2,1},{2,-12,2},{1,2,1}};

// Fused NCA step with perception FOLDED INTO GEMM1 (perception is linear):
//   Wfold[row][k], k = dy*40 + dx*12 + ch (rem 36..39 of each dy-slice = 0 pad;
//   k=120 = bias column with B=1.0 synthesized; 121..127 = 0).
//   B[k][px] = bf16 x[ch][h+dy-1][px+dx-1], read DIRECTLY from the transposed
//   bf16 LDS x tile [row][col][ch] as 2 contiguous ds_read_b64 per K-step.
// GEMM2 unchanged (verified): K-bijection col(s2,g,j)=32s2+16*(j>=4)+4g+(j&3),
// M-perm sigma(4g+r)=3g+r so acc2[r] = channel c0+r; GEMM1 D regs ARE GEMM2 B.
// LDS reused: phase1 Wfold[96][128] (24.5KB) -> A frags to regs -> phase2 x tile.
__global__ __launch_bounds__(256, 3) void nca_fused14(
    const float* __restrict__ x, const float* __restrict__ w1,
    const float* __restrict__ b1, const float* __restrict__ w2,
    const float* __restrict__ rmask, float* __restrict__ out)
{
    __shared__ unsigned short smem[12288];   // 24576 B (Wfold phase; x tile uses 9360+pad)

    const int tid  = threadIdx.x;
    const int lane = tid & 63;
    const int wv   = tid >> 6;
    const int g    = lane >> 4;   // 16-lane group (K-slice for A/B, row-slice for D)
    const int p    = lane & 15;   // pixel col (B/D), weight row (A)
    const int c0   = 3 * g;       // lane's epilogue channel base (sigma perm)

    // grid: 4096 blocks = 32 batches x 64 row-strips x 2 col-halves
    const int b     = blockIdx.x >> 7;
    const int strip = (blockIdx.x >> 1) & 63;
    const int half  = blockIdx.x & 1;
    const int ra    = strip << 2;
    const int c0g   = half << 7;
    const float* __restrict__ xb = x + (size_t)b * NC * NHW;
    const float* __restrict__ mb = rmask + (size_t)b * NHW;
    float* __restrict__ ob = out + (size_t)b * NC * NHW;

    const int h    = ra + wv;
    const int hrow = h << 8;

    float* obp[3];
    #pragma unroll
    for (int r = 0; r < 3; ++r) obp[r] = ob + (c0 + r)*NHW + hrow + c0g + p;
    const float* mbp = mb + hrow + c0g + p;

    // prefetch all 8 mask values (global latency) before anything else
    float mv[8];
    #pragma unroll
    for (int m = 0; m < 8; ++m) mv[m] = mbp[m << 4];

    // ---- phase 1: build Wfold in LDS (192 threads: row = tid>>1, half-ch) ----
    if (tid < 192) {
        const int row = tid >> 1;
        const int hh  = tid & 1;          // channels 6hh .. 6hh+5
        float wr[6][4];
        #pragma unroll
        for (int c6 = 0; c6 < 6; ++c6) {
            const float4 t4 = *reinterpret_cast<const float4*>(w1 + row*48 + (6*hh + c6)*4);
            wr[c6][0] = t4.x; wr[c6][1] = t4.y; wr[c6][2] = t4.z; wr[c6][3] = t4.w;
        }
        #pragma unroll
        for (int dy = 0; dy < 3; ++dy)
            #pragma unroll
            for (int dx = 0; dx < 3; ++dx) {
                float v[6];
                #pragma unroll
                for (int c6 = 0; c6 < 6; ++c6)
                    v[c6] = wr[c6][0]*FI[dy][dx] + wr[c6][1]*FX[dy][dx]
                          + wr[c6][2]*FY[dy][dx] + wr[c6][3]*FL[dy][dx];
                const int col = dy*40 + dx*12 + 6*hh;   // even -> u32-aligned
                #pragma unroll
                for (int e = 0; e < 3; ++e)
                    *reinterpret_cast<uint32_t*>(&smem[WSWZ(row, col + 2*e)]) = pkbf_c(v[2*e], v[2*e+1]);
            }
    }
    if (tid < 96) {   // pads + bias column
        const int row = tid;
        #pragma unroll
        for (int e = 0; e < 2; ++e) {
            *reinterpret_cast<uint32_t*>(&smem[WSWZ(row,  36 + 2*e)]) = 0u;
            *reinterpret_cast<uint32_t*>(&smem[WSWZ(row,  76 + 2*e)]) = 0u;
            *reinterpret_cast<uint32_t*>(&smem[WSWZ(row, 116 + 2*e)]) = 0u;
        }
        *reinterpret_cast<uint32_t*>(&smem[WSWZ(row, 120)]) = pkbf_c(b1[row], 0.f);  // bias, pad
        *reinterpret_cast<uint32_t*>(&smem[WSWZ(row, 122)]) = 0u;
        *reinterpret_cast<uint32_t*>(&smem[WSWZ(row, 124)]) = 0u;
        *reinterpret_cast<uint32_t*>(&smem[WSWZ(row, 126)]) = 0u;
    }
    __syncthreads();

    // ---- A fragments -> registers, pinned ----
    u32x4 a1f[6][4];
    #pragma unroll
    for (int t = 0; t < 6; ++t)
        #pragma unroll
        for (int s = 0; s < 4; ++s) {
            a1f[t][s] = *reinterpret_cast<const u32x4*>(&smem[WSWZ(16*t + p, 32*s + 8*g)]);
            PIN(a1f[t][s]);
        }
    u32x4 a2u[3];
    {
        const int rp = p & 3, gp = p >> 2;
        const int chA = 3*gp + rp;            // sigma(4g+r)=3g+r
        #pragma unroll
        for (int s = 0; s < 3; ++s) {
            u32x4 u = {0u, 0u, 0u, 0u};
            if (rp < 3) {
                const float4 wa = *reinterpret_cast<const float4*>(w2 + chA*96 + 32*s + 4*g);
                const float4 wb = *reinterpret_cast<const float4*>(w2 + chA*96 + 32*s + 16 + 4*g);
                u = (u32x4){ pkbf_c(wa.x, wa.y), pkbf_c(wa.z, wa.w), pkbf_c(wb.x, wb.y), pkbf_c(wb.z, wb.w) };
            }
            a2u[s] = u;
            PIN(a2u[s]);
        }
    }
    __syncthreads();   // everyone done reading Wfold before overwrite

    // ---- phase 2: stage x tile bf16 transposed [6 rows][130 cols][12 ch] ----
    {
        const int q = tid >> 5;        // (ch,row) pair slot 0..7
        const int l = tid & 31;        // 4-col chunk
        #pragma unroll
        for (int j = 0; j < 9; ++j) {
            const int pair = 8*j + q;              // 0..71
            const int c    = pair / 6;
            const int r_   = pair - 6*c;
            const int row  = (ra + 255 + r_) & 255;
            const f32x4 v = *reinterpret_cast<const f32x4*>(xb + c*NHW + (row << 8) + c0g + 4*l);
            const int base = r_*XROW + (1 + 4*l)*12 + c;
            smem[base]      = bf16u(v[0]);
            smem[base + 12] = bf16u(v[1]);
            smem[base + 24] = bf16u(v[2]);
            smem[base + 36] = bf16u(v[3]);
        }
        if (tid < 144) {               // 72 pairs x 2 wrap-halo cols
            const int pair = tid >> 1, side = tid & 1;
            const int c = pair / 6, r_ = pair - 6*c;
            const int row  = (ra + 255 + r_) & 255;
            const int gcol = side ? ((c0g + 128) & 255) : ((c0g + 255) & 255);
            smem[r_*XROW + (side ? 129 : 0)*12 + c] = bf16u(xb[c*NHW + (row << 8) + gcol]);
        }
    }
    __syncthreads();

    // ---- per-lane B-read bases: k0=32s+8g -> dy slice + remainder ----
    int bsE[4];
    #pragma unroll
    for (int s = 0; s < 4; ++s) {
        const int k0  = 32*s + 8*g;
        const int dy  = (k0 >= 40) + (k0 >= 80);
        const int rem = k0 - 40*dy;                       // multiple of 8 -> b64-aligned
        bsE[s] = ((wv + dy)*130 + p)*12 + rem;            // (g3,s3: garbage base, overridden)
    }
    const int xeE = ((wv + 1)*130 + 1 + p)*12 + c0;       // epilogue x (center, ch c0+r)

    #pragma unroll
    for (int grp = 0; grp < 8; ++grp) {
        const int o12 = grp * 192;     // 16 cols * 12 ch per body step (compile-time)

        // B fragments: 8 ds_read_b64, immediate offsets off fixed bases
        u32x4 fb[4];
        #pragma unroll
        for (int s = 0; s < 4; ++s) {
            const uint64_t lo = *reinterpret_cast<const uint64_t*>(&smem[bsE[s] + o12]);
            const uint64_t hi = *reinterpret_cast<const uint64_t*>(&smem[bsE[s] + o12 + 4]);
            fb[s] = (u32x4){ (uint32_t)lo, (uint32_t)(lo >> 32), (uint32_t)hi, (uint32_t)(hi >> 32) };
        }
        if (g == 3) fb[3] = (u32x4){ 0x00003F80u, 0u, 0u, 0u };   // k=120: B=1.0 (bias), rest A=0

        // ---- GEMM1: 24 MFMA over K=128 folded weights (stencil + bias inside) ----
        __builtin_amdgcn_s_setprio(1);
        uint32_t pu[6][2];
        #pragma unroll
        for (int t = 0; t < 6; ++t) {
            f32x4 acc = {0.f, 0.f, 0.f, 0.f};
            #pragma unroll
            for (int s = 0; s < 4; ++s)
                acc = __builtin_amdgcn_mfma_f32_16x16x32_bf16(
                    __builtin_bit_cast(bf16x8, a1f[t][s]), __builtin_bit_cast(bf16x8, fb[s]), acc, 0, 0, 0);
            pu[t][0] = pkbf(fmaxf(acc[0], 0.f), fmaxf(acc[1], 0.f));
            pu[t][1] = pkbf(fmaxf(acc[2], 0.f), fmaxf(acc[3], 0.f));
        }
        // ---- GEMM2: pu words ARE the B-frags under the K-bijection ----
        f32x4 acc2 = {0.f, 0.f, 0.f, 0.f};
        #pragma unroll
        for (int s2 = 0; s2 < 3; ++s2) {
            const u32x4 fb2 = { pu[2*s2][0], pu[2*s2][1], pu[2*s2+1][0], pu[2*s2+1][1] };
            acc2 = __builtin_amdgcn_mfma_f32_16x16x32_bf16(
                __builtin_bit_cast(bf16x8, a2u[s2]), __builtin_bit_cast(bf16x8, fb2), acc2, 0, 0, 0);
        }
        __builtin_amdgcn_s_setprio(0);

        // ---- epilogue: x center from bf16 tile, prefetched mask ----
        const float um = floorf(mv[grp] + 0.5f);
        const int o = grp << 4;
        #pragma unroll
        for (int r = 0; r < 3; ++r) {
            const uint32_t xu = (uint32_t)smem[xeE + o12 + r];
            const float xf = __builtin_bit_cast(float, xu << 16);
            obp[r][o] = xf + acc2[r] * um;
        }
    }
}

extern "C" void kernel_launch(void* const* d_in, const int* in_sizes, int n_in,
                              void* d_out, int out_size, void* d_ws, size_t ws_size,
                              hipStream_t stream) {
    const float* x  = (const float*)d_in[0];
    const float* w1 = (const float*)d_in[1];
    const float* b1 = (const float*)d_in[2];
    const float* w2 = (const float*)d_in[3];
    const float* rm = (const float*)d_in[4];
    float* out = (float*)d_out;
    nca_fused14<<<dim3(32 * 64 * 2), dim3(256), 0, stream>>>(x, w1, b1, w2, rm, out);
}